// Round 14
// baseline (253.057 us; speedup 1.0000x reference)
//
#include <hip/hip_runtime.h>

#define WD   192
#define HD   192
#define HWD  (WD*HD)
#define NCH  64
#define NOUT 64
#define NK   5
#define BAND 12
#define COLS 194
#define ROWB 128
#define XBF_OFF 256

typedef __attribute__((ext_vector_type(8))) short short8;
typedef __attribute__((ext_vector_type(4))) float f32x4;

__device__ inline ushort f2bf(float f) {
  union { float f; unsigned u; } xx; xx.f = f;
  unsigned u = xx.u;
  return (ushort)((u + 0x7FFFu + ((u >> 16) & 1u)) >> 16);   // RNE
}

__device__ inline int ldso(int slot, int pix, int cbyte) {
  int byte = (slot * COLS + pix) * ROWB + cbyte;
  return byte ^ ((pix & 7) << 4);
}

// taps[5..9] = dr ; taps[10..14] = dc
__global__ void prep_taps_k(const int* __restrict__ rot, int* __restrict__ taps) {
  const int ring_r[8] = {0,0,1,2,2,2,1,0};
  const int ring_c[8] = {1,2,2,2,1,0,0,0};
  int off = ((rot[0] % 8) + 8) % 8;
  for (int k = 0; k < 4; ++k) {
    int p = (2*k + off) & 7;
    taps[k] = 0; taps[5 + k] = ring_r[p] - 1; taps[10 + k] = ring_c[p] - 1;
  }
  taps[4] = 0; taps[9] = 0; taps[14] = 0;
}

__device__ inline void lds_barrier() {
  __builtin_amdgcn_sched_barrier(0);
  asm volatile("s_waitcnt lgkmcnt(0)" ::: "memory");
  __builtin_amdgcn_sched_barrier(0);
  __builtin_amdgcn_s_barrier();
  __builtin_amdgcn_sched_barrier(0);
}

// ---------- Pass 1: NCHW fp32 -> NHWC bf16 repack (memory-bound) ----------
__global__ __launch_bounds__(256) void repack_k(const float* __restrict__ x,
                                                ushort* __restrict__ xbf) {
  const int px = blockIdx.x * 256 + threadIdx.x;   // 0..HWD-1
  const int n  = blockIdx.y;
  const float* xp = x + (size_t)n * NCH * HWD + px;
  ushort* op = xbf + ((size_t)n * HWD + px) * NCH;
  #pragma unroll
  for (int c0 = 0; c0 < NCH; c0 += 16) {
    short8 b0, b1;
    #pragma unroll
    for (int j = 0; j < 8; ++j) b0[j] = (short)f2bf(xp[(size_t)(c0 + j) * HWD]);
    #pragma unroll
    for (int j = 0; j < 8; ++j) b1[j] = (short)f2bf(xp[(size_t)(c0 + 8 + j) * HWD]);
    *reinterpret_cast<short8*>(op + c0)     = b0;
    *reinterpret_cast<short8*>(op + c0 + 8) = b1;
  }
}

// ---------- Pass 2: barrier-free direct conv (reads xbf from L2/L3) ----------
// 1024 thr = 16 waves; wave = 16o x 48px; 16 waves/CU guaranteed resident.
__global__ __launch_bounds__(1024, 2) void rconv_direct_k(
    const ushort* __restrict__ xbf, const float* __restrict__ w,
    const int* __restrict__ taps, float* __restrict__ out) {
  const int tid  = threadIdx.x;
  const int lane = tid & 63;
  const int wv   = tid >> 6;        // 0..15
  const int l15  = lane & 15;
  const int g    = lane >> 4;       // 0..3
  const int r0   = blockIdx.x * BAND;
  const int n    = blockIdx.y;
  const int o0w  = (wv & 3) * 16;   // o-group (16 o)
  const int wq   = wv >> 2;         // pixel quarter (48 px)

  int dr[NK], dc[NK];
  #pragma unroll
  for (int k = 0; k < NK; ++k) { dr[k] = taps[5 + k]; dc[k] = taps[10 + k]; }

  // W fragments (40 VGPR), used in MFMA *B* position (N=o via l15):
  // a[kc][k] elem j = W[o0w+l15][kc*32+g*8+j][k]
  short8 a[2][NK];
  #pragma unroll
  for (int kc = 0; kc < 2; ++kc)
    #pragma unroll
    for (int k = 0; k < NK; ++k) {
      short8 t;
      #pragma unroll
      for (int j = 0; j < 8; ++j)
        t[j] = (short)f2bf(w[(size_t)(o0w + l15) * (NCH*NK)
                             + (kc*32 + g*8 + j) * NK + k]);
      a[kc][k] = t;
    }

  const ushort* xb = xbf + (size_t)n * HWD * NCH;   // [h][w][c]

  #pragma unroll 1
  for (int r = r0; r < r0 + BAND; ++r) {
    f32x4 acc[3];
    #pragma unroll
    for (int t = 0; t < 3; ++t) acc[t] = (f32x4){0.f, 0.f, 0.f, 0.f};

    #pragma unroll
    for (int k = 0; k < NK; ++k) {
      int row = r + dr[k];
      if ((unsigned)row < (unsigned)HD) {   // uniform; OOB row-tap contributes 0
        const ushort* rb = xb + (size_t)row * WD * NCH;
        #pragma unroll
        for (int t = 0; t < 3; ++t) {
          int p = wq * 48 + dc[k] + t * 16 + l15;           // -1..192 at edges
          const bool maskable = (wq == 0 && t == 0 && dc[k] < 0) ||
                                (wq == 3 && t == 2 && dc[k] > 0);   // uniform
          int pc = p < 0 ? 0 : (p >= WD ? WD - 1 : p);
          const ushort* fp = rb + (size_t)pc * NCH + g * 8;
          // x-fragment (A position): lane l15 = pixel row of D; elems =
          // channels kc*32+g*8+j — one dwordx4 per fragment, 16 full
          // 64B-lines per wave instr.
          short8 b0 = *reinterpret_cast<const short8*>(fp);
          short8 b1 = *reinterpret_cast<const short8*>(fp + 32);
          if (maskable) {
            if (p < 0 || p >= WD) {       // divergent only on 1 lane
              b0 = (short8){0,0,0,0,0,0,0,0};
              b1 = (short8){0,0,0,0,0,0,0,0};
            }
          }
          acc[t] = __builtin_amdgcn_mfma_f32_16x16x32_bf16(b0, a[0][k], acc[t], 0, 0, 0);
          acc[t] = __builtin_amdgcn_mfma_f32_16x16x32_bf16(b1, a[1][k], acc[t], 0, 0, 0);
        }
      }
    }
    // D: col(l15)=o, rows(4g+q)=4 consecutive pixels -> dwordx4 stores
    #pragma unroll
    for (int t = 0; t < 3; ++t) {
      size_t ob = ((size_t)(n * NOUT + o0w + l15)) * HWD
                + (size_t)r * WD + wq * 48 + t * 16 + 4 * g;
      *reinterpret_cast<f32x4*>(&out[ob]) = acc[t];
    }
  }
}

// ---------- Fallback: R13 ring kernel (proven 78.9 µs) ----------
__global__ __launch_bounds__(512, 2) void rconv_ring_k(
    const float* __restrict__ x, const float* __restrict__ w,
    const int* __restrict__ taps, float* __restrict__ out) {
  __shared__ ushort lds[4 * COLS * (ROWB / 2)];
  char* ldsb = (char*)lds;
  const int tid  = threadIdx.x;
  const int lane = tid & 63;
  const int wv   = tid >> 6;
  const int l15  = lane & 15;
  const int g    = lane >> 4;
  const int r0   = blockIdx.x * BAND;
  const int n    = blockIdx.y;
  const int o0w  = (wv & 1) * 32;
  const int wq   = wv >> 1;

  int dr[NK], dc[NK];
  #pragma unroll
  for (int k = 0; k < NK; ++k) { dr[k] = taps[5 + k]; dc[k] = taps[10 + k]; }

  short8 a[2][2][NK];
  #pragma unroll
  for (int ot = 0; ot < 2; ++ot)
    #pragma unroll
    for (int kc = 0; kc < 2; ++kc)
      #pragma unroll
      for (int k = 0; k < NK; ++k) {
        short8 t;
        #pragma unroll
        for (int j = 0; j < 8; ++j)
          t[j] = (short)f2bf(w[(size_t)(o0w + ot*16 + l15) * (NCH*NK)
                               + (kc*32 + g*8 + j) * NK + k]);
        a[ot][kc][k] = t;
      }

  const float* xn = x + ((size_t)n * NCH + wv * 8) * HWD;
  auto stage_load = [&](int gr, float v[3][8]) {
    bool vr = (gr >= 0) && (gr < HD);
    if (vr) {
      const float* xr = xn + (size_t)gr * WD;
      #pragma unroll
      for (int i = 0; i < 3; ++i)
        #pragma unroll
        for (int j = 0; j < 8; ++j)
          v[i][j] = xr[(size_t)j * HWD + i * 64 + lane];
    } else {
      #pragma unroll
      for (int i = 0; i < 3; ++i)
        #pragma unroll
        for (int j = 0; j < 8; ++j) v[i][j] = 0.f;
    }
  };
  auto stage_write = [&](int gr, const float v[3][8]) {
    int s = gr & 3;
    #pragma unroll
    for (int i = 0; i < 3; ++i) {
      short8 t;
      #pragma unroll
      for (int j = 0; j < 8; ++j) t[j] = (short)f2bf(v[i][j]);
      *reinterpret_cast<short8*>(ldsb + ldso(s, 1 + i * 64 + lane, wv * 16)) = t;
    }
  };
  f32x4 acc[3][2];
  auto compute_row = [&](int r) {
    int bo0[NK], bo1[NK];
    #pragma unroll
    for (int k = 0; k < NK; ++k) {
      int pix = wq * 48 + dc[k] + 1 + l15;
      bo0[k] = ldso((r + dr[k]) & 3, pix, g * 16);
      bo1[k] = ldso((r + dr[k]) & 3, pix, g * 16 + 64);
    }
    #pragma unroll
    for (int t = 0; t < 3; ++t) {
      acc[t][0] = (f32x4){0.f, 0.f, 0.f, 0.f};
      acc[t][1] = (f32x4){0.f, 0.f, 0.f, 0.f};
    }
    __builtin_amdgcn_s_setprio(1);
    #pragma unroll
    for (int t = 0; t < 3; ++t)
      #pragma unroll
      for (int k = 0; k < NK; ++k) {
        short8 b0 = *reinterpret_cast<const short8*>(ldsb + bo0[k] + t * 16 * ROWB);
        short8 b1 = *reinterpret_cast<const short8*>(ldsb + bo1[k] + t * 16 * ROWB);
        acc[t][0] = __builtin_amdgcn_mfma_f32_16x16x32_bf16(b0, a[0][0][k], acc[t][0], 0, 0, 0);
        acc[t][1] = __builtin_amdgcn_mfma_f32_16x16x32_bf16(b0, a[1][0][k], acc[t][1], 0, 0, 0);
        acc[t][0] = __builtin_amdgcn_mfma_f32_16x16x32_bf16(b1, a[0][1][k], acc[t][0], 0, 0, 0);
        acc[t][1] = __builtin_amdgcn_mfma_f32_16x16x32_bf16(b1, a[1][1][k], acc[t][1], 0, 0, 0);
      }
    __builtin_amdgcn_s_setprio(0);
  };
  auto store_row = [&](int r) {
    #pragma unroll
    for (int t = 0; t < 3; ++t)
      #pragma unroll
      for (int ot = 0; ot < 2; ++ot) {
        size_t ob = ((size_t)(n * NOUT + o0w + ot * 16 + l15)) * HWD
                  + (size_t)r * WD + wq * 48 + t * 16 + 4 * g;
        *reinterpret_cast<f32x4*>(&out[ob]) = acc[t][ot];
      }
  };
  float vA[3][8], vB[3][8];
  if (tid < 64) {
    short8 z = (short8){0,0,0,0,0,0,0,0};
    int slot = tid >> 4, px = ((tid >> 3) & 1) * (COLS - 1), cb = (tid & 7) * 16;
    *reinterpret_cast<short8*>(ldsb + ldso(slot, px, cb)) = z;
  }
  stage_load(r0 - 1, vA); stage_write(r0 - 1, vA);
  stage_load(r0,     vA); stage_write(r0,     vA);
  stage_load(r0 + 1, vA); stage_write(r0 + 1, vA);
  stage_load(r0 + 2, vA);
  lds_barrier();
  #pragma unroll 1
  for (int i = 0; i < BAND / 2; ++i) {
    int r = r0 + 2 * i;
    {
      if (r + 3 <= r0 + BAND) stage_load(r + 3, vB);
      compute_row(r);
      stage_write(r + 2, vA);
      lds_barrier();
      store_row(r);
    }
    {
      int r1 = r + 1;
      if (r1 + 3 <= r0 + BAND) stage_load(r1 + 3, vA);
      compute_row(r1);
      if (r1 + 2 <= r0 + BAND) stage_write(r1 + 2, vB);
      lds_barrier();
      store_row(r1);
    }
  }
}

extern "C" void kernel_launch(void* const* d_in, const int* in_sizes, int n_in,
                              void* d_out, int out_size, void* d_ws, size_t ws_size,
                              hipStream_t stream) {
  const float* x = (const float*)d_in[0];
  const float* w = (const float*)d_in[1];
  const int* rot = (const int*)d_in[2];
  float* out     = (float*)d_out;
  int* taps      = (int*)d_ws;

  const int nbatch = in_sizes[0] / (NCH * HWD);   // 16
  const size_t need = (size_t)XBF_OFF + (size_t)nbatch * HWD * NCH * 2;

  hipLaunchKernelGGL(prep_taps_k, dim3(1), dim3(1), 0, stream, rot, taps);
  if (ws_size >= need) {
    ushort* xbf = (ushort*)((char*)d_ws + XBF_OFF);
    hipLaunchKernelGGL(repack_k, dim3(HWD / 256, nbatch), dim3(256), 0, stream,
                       x, xbf);
    hipLaunchKernelGGL(rconv_direct_k, dim3(HD / BAND, nbatch), dim3(1024), 0,
                       stream, xbf, w, taps, out);
  } else {
    hipLaunchKernelGGL(rconv_ring_k, dim3(HD / BAND, nbatch), dim3(512), 0,
                       stream, x, w, taps, out);
  }
}